// Round 1
// baseline (161.139 us; speedup 1.0000x reference)
//
#include <hip/hip_runtime.h>

// Problem constants
static constexpr int NB   = 128;   // batch
static constexpr int NCIN = 64;    // input channels
static constexpr int NG   = 8;     // groups
static constexpr int NH   = 14;    // spatial
static constexpr int NP   = 16;    // mixed width
static constexpr int NJ   = 32;    // conv out channels
static constexpr int HH   = NH * NH;       // 196
static constexpr int LROW = 20;    // padded LDS row (l in [-2,17])

// ---------------------------------------------------------------------------
// Kernel 1: channel mix.  t4[b][g][m][l][p] = sum_j x[b][j][g][m][l]*wmix[j][p]
// thread = (b, g, squad) with squad indexing 4 consecutive spatial positions
// (196 = 49*4 exactly -> aligned float4 loads/stores).
// wmix accesses are wave-uniform -> compiler emits scalar loads (SGPR operands).
// ---------------------------------------------------------------------------
__global__ __launch_bounds__(64) void mix_kernel(const float* __restrict__ x,
                                                 const float* __restrict__ wmix,
                                                 float* __restrict__ t4) {
    int t     = blockIdx.x * 64 + threadIdx.x;   // 0 .. 50175
    int squad = t % 49;
    int bg    = t / 49;                          // b*8 + g
    int b     = bg >> 3;
    int g     = bg & 7;

    float acc[4][NP];
#pragma unroll
    for (int q = 0; q < 4; q++)
#pragma unroll
        for (int p = 0; p < NP; p++) acc[q][p] = 0.f;

    const float* xbase = x + (size_t)b * (NCIN * NG * HH) + (size_t)g * HH + squad * 4;

#pragma unroll 4
    for (int j = 0; j < NCIN; j++) {
        float4 xv = *reinterpret_cast<const float4*>(xbase + (size_t)j * (NG * HH));
#pragma unroll
        for (int p = 0; p < NP; p++) {
            float w = wmix[j * NP + p];          // uniform -> s_load
            acc[0][p] += xv.x * w;
            acc[1][p] += xv.y * w;
            acc[2][p] += xv.z * w;
            acc[3][p] += xv.w * w;
        }
    }

    float* tb = t4 + ((size_t)bg * HH + squad * 4) * NP;
#pragma unroll
    for (int q = 0; q < 4; q++)
#pragma unroll
        for (int p4 = 0; p4 < 4; p4++) {
            *reinterpret_cast<float4*>(tb + q * NP + p4 * 4) =
                make_float4(acc[q][p4 * 4 + 0], acc[q][p4 * 4 + 1],
                            acc[q][p4 * 4 + 2], acc[q][p4 * 4 + 3]);
        }
}

// ---------------------------------------------------------------------------
// Kernel 2: 5-tap grouped conv along l + roll + output transpose.
// block = (b, o); 128 threads, lane = (p, jg); n (0..13) is a register dim.
// out[b][(j*16+p)][o][n] = sum_{g,d} t4[b][g][o_src][n+d-2][p] * W2[g][d][j]
//   - (n==0)  correction wconv[g][0][2][j]*t4[l=0]
//   - (n==13) correction wconv[g][2][0][j]*t4[l=13]
// ---------------------------------------------------------------------------
__global__ __launch_bounds__(128) void conv_kernel(const float* __restrict__ t4,
                                                   const float* __restrict__ wconv,
                                                   float* __restrict__ out) {
    __shared__ __align__(16) float lds[512 * 15];          // 30720 B
    float* t4s = lds;               // [8][16][LROW] = 2560 floats
    float* w2s = lds + 2560;        // [8][5][32]    = 1280 floats
    float* wcs = lds + 3840;        // [2][8][32]    =  512 floats

    const int tid   = threadIdx.x;
    const int b     = blockIdx.x / NH;
    const int o     = blockIdx.x % NH;
    const int o_src = (o + NH - 1) % NH;

    // ---- stage t4 slice (coalesced read, transposed LDS write) ----
    const float* tsl = t4 + ((size_t)b * NG * HH + (size_t)o_src * NH) * NP;
#pragma unroll
    for (int r = 0; r < 14; r++) {                 // 1792 elements
        int idx = r * 128 + tid;
        int g   = idx / 224;                        // 14*16
        int rem = idx % 224;
        int l   = rem / 16;
        int p   = rem % 16;
        t4s[(g * 16 + p) * LROW + (l + 2)] = tsl[(size_t)g * HH * NP + l * 16 + p];
    }
    // zero pads: l2 in {0,1,16,17,18,19}
#pragma unroll
    for (int r = 0; r < 6; r++) {                  // 768 entries
        int idx = r * 128 + tid;
        int gp  = idx / 6;
        int s   = idx % 6;
        int l2  = (s < 2) ? s : (14 + s);
        t4s[gp * LROW + l2] = 0.f;
    }
    // W2[g][d][j] = sum_{i+k==d} wconv[g][i][k][j]
#pragma unroll
    for (int r = 0; r < 10; r++) {                 // 1280 entries
        int idx = r * 128 + tid;
        int g   = idx / 160;
        int di  = (idx / 32) % 5;
        int j   = idx % 32;
        int ilo = di > 2 ? di - 2 : 0;
        int ihi = di < 2 ? di : 2;
        float s = 0.f;
        for (int i = ilo; i <= ihi; i++) {
            int k = di - i;
            s += wconv[((g * 3 + i) * 3 + k) * 32 + j];
        }
        w2s[idx] = s;
    }
    // corrections: wcs[0][g][j] = wconv[g][0][2][j]; wcs[1][g][j] = wconv[g][2][0][j]
#pragma unroll
    for (int r = 0; r < 4; r++) {                  // 512 entries
        int idx = r * 128 + tid;
        int sel = idx / 256;
        int g   = (idx / 32) % 8;
        int j   = idx % 32;
        wcs[idx] = wconv[(g * 9 + (sel ? 6 : 2)) * 32 + j];
    }
    __syncthreads();

    const int p     = tid & 15;
    const int jg    = tid >> 4;     // 0..7
    const int jbase = jg * 4;

    float acc[NH][4];
#pragma unroll
    for (int n = 0; n < NH; n++) {
        acc[n][0] = 0.f; acc[n][1] = 0.f; acc[n][2] = 0.f; acc[n][3] = 0.f;
    }

    for (int g = 0; g < NG; g++) {
        float row[LROW];
        const float* rp = &t4s[(g * 16 + p) * LROW];
#pragma unroll
        for (int q = 0; q < 5; q++) {
            float4 v = *reinterpret_cast<const float4*>(rp + q * 4);
            row[q * 4 + 0] = v.x; row[q * 4 + 1] = v.y;
            row[q * 4 + 2] = v.z; row[q * 4 + 3] = v.w;
        }
#pragma unroll
        for (int di = 0; di < 5; di++) {
            float4 w = *reinterpret_cast<const float4*>(&w2s[(g * 5 + di) * 32 + jbase]);
#pragma unroll
            for (int n = 0; n < NH; n++) {
                float rv = row[n + di];
                acc[n][0] += rv * w.x;
                acc[n][1] += rv * w.y;
                acc[n][2] += rv * w.z;
                acc[n][3] += rv * w.w;
            }
        }
        float4 c0 = *reinterpret_cast<const float4*>(&wcs[g * 32 + jbase]);
        float4 c1 = *reinterpret_cast<const float4*>(&wcs[256 + g * 32 + jbase]);
        float r2 = row[2], r15 = row[15];
        acc[0][0]  -= r2  * c0.x; acc[0][1]  -= r2  * c0.y;
        acc[0][2]  -= r2  * c0.z; acc[0][3]  -= r2  * c0.w;
        acc[13][0] -= r15 * c1.x; acc[13][1] -= r15 * c1.y;
        acc[13][2] -= r15 * c1.z; acc[13][3] -= r15 * c1.w;
    }

    __syncthreads();   // done reading t4s/w2s/wcs; reuse lds as output stage

    // stage results: outs[c*15 + n], c = (jbase+jj)*16 + p  (stride 15 -> low conflict)
#pragma unroll
    for (int jj = 0; jj < 4; jj++) {
        int c = (jbase + jj) * 16 + p;
#pragma unroll
        for (int n = 0; n < NH; n++) lds[c * 15 + n] = acc[n][jj];
    }
    __syncthreads();

    // coalesced-ish write: contiguous 14-float runs per channel
    float* ob = out + (size_t)b * 512 * HH + (size_t)o * NH;
#pragma unroll
    for (int r = 0; r < 56; r++) {                 // 7168 = 512*14
        int idx = r * 128 + tid;
        int c   = idx / 14;
        int n   = idx % 14;
        ob[(size_t)c * HH + n] = lds[c * 15 + n];
    }
}

extern "C" void kernel_launch(void* const* d_in, const int* in_sizes, int n_in,
                              void* d_out, int out_size, void* d_ws, size_t ws_size,
                              hipStream_t stream) {
    const float* x     = (const float*)d_in[0];
    const float* wconv = (const float*)d_in[1];
    const float* wmix  = (const float*)d_in[2];
    float* out = (float*)d_out;
    float* t4  = (float*)d_ws;   // 128*8*196*16 floats = 12.85 MB scratch

    // Kernel 1: 50176 threads = 784 blocks * 64
    mix_kernel<<<784, 64, 0, stream>>>(x, wmix, t4);
    // Kernel 2: one block per (b, o)
    conv_kernel<<<NB * NH, 128, 0, stream>>>(t4, wconv, out);
}